// Round 1
// baseline (1854.155 us; speedup 1.0000x reference)
//
#include <hip/hip_runtime.h>
#include <stdint.h>

#define NN 2048
#define DD 512
#define NWORDS 8

typedef unsigned int u32;
typedef unsigned char u8;

__device__ __forceinline__ float sigmoidf_(float x){ return 1.0f/(1.0f+expf(-x)); }

// ---------------- build adjacency bitmask ----------------
__global__ void k_zero_bm(u32* bm){ int t = blockIdx.x*256+threadIdx.x; if(t<NN*NWORDS) bm[t]=0u; }

__global__ void k_scatter(const int* __restrict__ ei, u32* __restrict__ bm){
  int t = blockIdx.x*256+threadIdx.x;
  if(t>=32768) return;
  int r = ei[t];
  int c = ei[32768+t];
  atomicOr(&bm[r*NWORDS + ((c>>5)&7)], 1u<<(c&31));
}

// bm2[r] = OR over neighbors k of bm[k]  (i.e. bit c set iff A2[r][c]>0); deg[r]=popcount(row)
__global__ void k_bm2_deg(const u32* __restrict__ bm, u32* __restrict__ bm2, int* __restrict__ deg){
  int r = blockIdx.x*256+threadIdx.x;
  if(r>=NN) return;
  int base = r & ~255;
  u32 acc[NWORDS];
  #pragma unroll
  for(int w=0;w<NWORDS;++w) acc[w]=0u;
  int d=0;
  #pragma unroll
  for(int w=0;w<NWORDS;++w){
    u32 m = bm[r*NWORDS+w];
    d += __popc(m);
    int b0 = w<<5;
    while(m){ int j=__ffs((int)m)-1; m&=m-1;
      const u32* row = bm + (size_t)(base+b0+j)*NWORDS;
      #pragma unroll
      for(int w2=0;w2<NWORDS;++w2) acc[w2] |= row[w2];
    }
  }
  #pragma unroll
  for(int w=0;w<NWORDS;++w) bm2[r*NWORDS+w]=acc[w];
  deg[r]=d;
}

// ---------------- Vn = ||deg*x^2 - 2x*Ax + A@(x^2)||_row ----------------
__global__ void k_vn(const float* __restrict__ x, const u32* __restrict__ bm,
                     const int* __restrict__ deg, float* __restrict__ Vn){
  int node = blockIdx.x*4 + (threadIdx.x>>6);
  int lane = threadIdx.x & 63;
  int base = node & ~255;
  float degf = (float)deg[node];
  float ax[8], axx[8];
  #pragma unroll
  for(int k=0;k<8;++k){ ax[k]=0.0f; axx[k]=0.0f; }
  #pragma unroll
  for(int w=0;w<NWORDS;++w){
    u32 m = bm[node*NWORDS+w]; int b0=w<<5;
    while(m){ int j=__ffs((int)m)-1; m&=m-1;
      const float* xr = x + (size_t)(base+b0+j)*DD;
      #pragma unroll
      for(int k=0;k<8;++k){ float v = xr[lane+64*k]; ax[k]+=v; axx[k]=fmaf(v,v,axx[k]); }
    }
  }
  const float* xi = x + (size_t)node*DD;
  double vn2 = 0.0;
  #pragma unroll
  for(int k=0;k<8;++k){
    float xf = xi[lane+64*k];
    float val = xf*(degf*xf - ax[k]) - xf*ax[k] + axx[k];
    vn2 += (double)val*(double)val;
  }
  #pragma unroll
  for(int off=32;off>0;off>>=1) vn2 += __shfl_down(vn2, off);
  if(lane==0) Vn[node] = (float)sqrt(vn2);
}

// ---------------- per-graph softmax entropy ----------------
__global__ void k_softent(const float* __restrict__ Vn, float* __restrict__ ent){
  __shared__ float red[4];
  __shared__ float sh;
  int g = blockIdx.x, tid = threadIdx.x;
  float v = Vn[g*256+tid];
  float m = v;
  #pragma unroll
  for(int off=32;off>0;off>>=1) m = fmaxf(m, __shfl_down(m,off));
  if((tid&63)==0) red[tid>>6]=m;
  __syncthreads();
  if(tid==0) sh = fmaxf(fmaxf(red[0],red[1]),fmaxf(red[2],red[3]));
  __syncthreads();
  float mx = sh;
  float e = expf(v-mx);
  float s = e;
  #pragma unroll
  for(int off=32;off>0;off>>=1) s += __shfl_down(s,off);
  if((tid&63)==0) red[tid>>6]=s;
  __syncthreads();
  if(tid==0) sh = red[0]+red[1]+red[2]+red[3];
  __syncthreads();
  float Pn = e / sh;
  if(Pn==0.0f) Pn=1.0f;
  ent[g*256+tid] = -Pn*logf(Pn);
}

// u = ent + A@ent
__global__ void k_u(const u32* __restrict__ bm, const float* __restrict__ ent, float* __restrict__ uo){
  int i = blockIdx.x*256+threadIdx.x;
  if(i>=NN) return;
  int base = i & ~255;
  float acc = ent[i];
  #pragma unroll
  for(int w=0;w<NWORDS;++w){
    u32 m = bm[i*NWORDS+w]; int b0=w<<5;
    while(m){ int j=__ffs((int)m)-1; m&=m-1; acc += ent[base+b0+j]; }
  }
  uo[i]=acc;
}

// h1 = relu(u * w11 + b11)  (rank-1 input layer)
__global__ void k_h1(const float* __restrict__ u, const float* __restrict__ w11,
                     const float* __restrict__ b11, float* __restrict__ h){
  int t = blockIdx.x*256+threadIdx.x;
  if(t>=NN*DD) return;
  int i = t>>9; int f = t&511;
  h[t] = fmaxf(fmaf(u[i], w11[f], b11[f]), 0.0f);
}

// ---------------- tiled fp32 GEMM: C[2048x512] = act(A @ B + bias) ----------------
template<int ACT> // 0=relu 1=sigmoid
__global__ __launch_bounds__(256) void k_gemm(const float* __restrict__ A, const float* __restrict__ B,
                                              const float* __restrict__ bias, float* __restrict__ C){
  __shared__ float As[32][68];
  __shared__ float Bs[32][68];
  int tid = threadIdx.x;
  int m0 = blockIdx.x*64;
  int n0 = blockIdx.y*64;
  int ty = tid>>4, tx = tid&15;
  float acc[4][4];
  #pragma unroll
  for(int i=0;i<4;++i){
    #pragma unroll
    for(int j=0;j<4;++j) acc[i][j]=0.0f;
  }
  for(int k0=0;k0<512;k0+=32){
    __syncthreads();
    #pragma unroll
    for(int t0=0;t0<2;++t0){
      int t = tid + t0*256;
      int row = t>>3, c4 = t&7;
      float4 v = *(const float4*)(A + (size_t)(m0+row)*512 + k0 + c4*4);
      As[c4*4+0][row]=v.x; As[c4*4+1][row]=v.y; As[c4*4+2][row]=v.z; As[c4*4+3][row]=v.w;
    }
    #pragma unroll
    for(int t0=0;t0<2;++t0){
      int t = tid + t0*256;
      int row = t>>4, c4 = t&15;
      float4 v = *(const float4*)(B + (size_t)(k0+row)*512 + n0 + c4*4);
      *(float4*)&Bs[row][c4*4] = v;
    }
    __syncthreads();
    #pragma unroll
    for(int kk=0;kk<32;++kk){
      float4 a = *(const float4*)&As[kk][ty*4];
      float4 b = *(const float4*)&Bs[kk][tx*4];
      float av[4]={a.x,a.y,a.z,a.w}, bv[4]={b.x,b.y,b.z,b.w};
      #pragma unroll
      for(int i=0;i<4;++i){
        #pragma unroll
        for(int j=0;j<4;++j) acc[i][j] = fmaf(av[i],bv[j],acc[i][j]);
      }
    }
  }
  #pragma unroll
  for(int i=0;i<4;++i){
    float4 o;
    float* oo = &o.x;
    #pragma unroll
    for(int j=0;j<4;++j){
      float v = acc[i][j] + bias[n0+tx*4+j];
      if(ACT==0) v = fmaxf(v,0.0f);
      else      v = 1.0f/(1.0f+expf(-v));
      oo[j]=v;
    }
    *(float4*)(C + (size_t)(m0+ty*4+i)*512 + n0 + tx*4) = o;
  }
}

// out = h + A@h  (wave per node)
__global__ void k_spmm_add(const float* __restrict__ h, const u32* __restrict__ bm, float* __restrict__ out){
  int node = blockIdx.x*4 + (threadIdx.x>>6);
  int lane = threadIdx.x & 63;
  int base = node & ~255;
  float acc[8];
  #pragma unroll
  for(int k=0;k<8;++k) acc[k] = h[(size_t)node*DD + lane + 64*k];
  #pragma unroll
  for(int w=0;w<NWORDS;++w){
    u32 m = bm[node*NWORDS+w]; int b0=w<<5;
    while(m){ int j=__ffs((int)m)-1; m&=m-1;
      const float* hr = h + (size_t)(base+b0+j)*DD;
      #pragma unroll
      for(int k=0;k<8;++k) acc[k] += hr[lane+64*k];
    }
  }
  #pragma unroll
  for(int k=0;k<8;++k) out[(size_t)node*DD + lane + 64*k] = acc[k];
}

// z = sigmoid(h@w33 + b33); prob = sigmoid(z)
__global__ void k_gemv_prob(const float* __restrict__ h, const float* __restrict__ w33,
                            const float* __restrict__ b33, float* __restrict__ prob){
  int node = blockIdx.x*4 + (threadIdx.x>>6);
  int lane = threadIdx.x & 63;
  float acc = 0.0f;
  #pragma unroll
  for(int k=0;k<8;++k) acc = fmaf(h[(size_t)node*512 + lane + 64*k], w33[lane+64*k], acc);
  #pragma unroll
  for(int off=32;off>0;off>>=1) acc += __shfl_down(acc, off);
  if(lane==0){
    float z = sigmoidf_(acc + b33[0]);
    prob[node] = sigmoidf_(z);
  }
}

// ---------------- bitonic sort: order = argsort(-prob) stable ----------------
__global__ void k_sort(const float* __restrict__ prob, int* __restrict__ order){
  __shared__ float kp[NN];
  __shared__ int ki[NN];
  int tid = threadIdx.x; // 1024
  for(int t=tid;t<NN;t+=1024){ kp[t]=prob[t]; ki[t]=t; }
  __syncthreads();
  for(int k=2;k<=NN;k<<=1){
    for(int j=k>>1;j>0;j>>=1){
      for(int t=tid;t<NN;t+=1024){
        int l = t ^ j;
        if(l > t){
          bool up = ((t & k) == 0);
          float pa=kp[t]; int ia=ki[t]; float pb=kp[l]; int ib=ki[l];
          bool before_ab = (pa > pb) || (pa == pb && ia < ib);
          bool dosw = up ? (!before_ab) : before_ab;
          if(dosw){ kp[t]=pb; ki[t]=ib; kp[l]=pa; ki[l]=ia; }
        }
      }
      __syncthreads();
    }
  }
  for(int t=tid;t<NN;t+=1024) order[t]=ki[t];
}

// ---------------- sequential greedy scan (single workgroup) ----------------
__device__ __forceinline__ double block_reduce_d(double v, double* red, int tid){
  #pragma unroll
  for(int off=32;off>0;off>>=1) v += __shfl_down(v, off);
  if((tid&63)==0) red[tid>>6]=v;
  __syncthreads();
  double r=0.0;
  if(tid==0) r = red[0]+red[1]+red[2]+red[3];
  return r; // valid on tid 0 only; caller must __syncthreads() before next reduce
}

__global__ void k_scan(const u32* __restrict__ bm, const int* __restrict__ deg,
                       const float* __restrict__ ent, const float* __restrict__ prob,
                       const int* __restrict__ order, float* __restrict__ selw,
                       float* __restrict__ out_sel, float* __restrict__ out_loss){
  extern __shared__ char smem[];
  double* dsc = (double*)smem;            // [0]=gamma [1]=loss [2]=totC [3..10]=cblk[8]
  double* red = dsc + 12;                 // 4 doubles
  u32* bm_s = (u32*)(red + 4);            // 16384 u32
  float* dummy_s = (float*)(bm_s + NN*NWORDS);
  float* entf_s = dummy_s + NN;
  float* sbuf = entf_s + NN;              // 256
  int* order_s = (int*)(sbuf + 256);      // 2048
  int* ctl = order_s + NN;                // 4
  u8* sel_s = (u8*)(ctl + 4);
  u8* rej_s = sel_s + NN;
  int tid = threadIdx.x;

  for(int t=tid;t<NN*NWORDS;t+=256) bm_s[t]=bm[t];
  for(int t=tid;t<NN;t+=256){
    dummy_s[t]=prob[t];
    entf_s[t]=ent[t];
    order_s[t]=order[t];
    sel_s[t] = (deg[t]==0)?1:0;
    rej_s[t]=0;
  }
  __syncthreads();

  // gamma
  double gl=0.0;
  for(int t=tid;t<NN;t+=256) gl += (double)entf_s[t];
  gl = block_reduce_d(gl, red, tid);
  if(tid==0){ dsc[0]=gl; dsc[2]=0.0; }
  __syncthreads();

  // initial per-block contributions c_g = -entf.dummy + dummy.(A dummy)
  for(int g=0;g<8;++g){
    int base=g<<8;
    float sc = dummy_s[base+tid];
    sbuf[tid]=sc;
    __syncthreads();
    double As=0.0;
    {
      const u32* row = bm_s + (size_t)(base+tid)*NWORDS;
      #pragma unroll
      for(int w=0;w<NWORDS;++w){ u32 m=row[w]; int b0=w<<5;
        while(m){ int j=__ffs((int)m)-1; m&=m-1; As += (double)sbuf[b0+j]; } }
    }
    double val = (double)sc*As - (double)entf_s[base+tid]*(double)sc;
    val = block_reduce_d(val, red, tid);
    if(tid==0){ dsc[3+g]=val; dsc[2]+=val; }
    __syncthreads();
  }
  if(tid==0){ dsc[1]=dsc[0]+dsc[2]; out_loss[0]=(float)dsc[1]; }
  __syncthreads();

  // main sequential loop
  for(int t=0;t<NN;++t){
    if(tid==0){
      int node = order_s[t];
      // deg==0 nodes: sel preset at init; never eligible, no state change needed
      ctl[0] = (!sel_s[node] && !rej_s[node]) ? 1 : 0;
      ctl[1] = node;
    }
    __syncthreads();
    if(ctl[0]){
      int node = ctl[1];
      int base = node & ~255;
      int r = node & 255;
      u32 w = bm_s[(size_t)node*NWORDS + (tid>>5)];
      int isnb = (w >> (tid&31)) & 1;
      float sc = (tid==r) ? 1.0f : (isnb ? 0.0f : dummy_s[base+tid]);
      sbuf[tid]=sc;
      __syncthreads();
      double As=0.0;
      {
        const u32* row = bm_s + (size_t)(base+tid)*NWORDS;
        #pragma unroll
        for(int ww=0;ww<NWORDS;++ww){ u32 m=row[ww]; int b0=ww<<5;
          while(m){ int j=__ffs((int)m)-1; m&=m-1; As += (double)sbuf[b0+j]; } }
      }
      double val = (double)sc*As - (double)entf_s[base+tid]*(double)sc;
      val = block_reduce_d(val, red, tid);
      if(tid==0){
        int g = node>>8;
        double l = dsc[0] + dsc[2] - dsc[3+g] + val;
        int take = (l <= dsc[1]) ? 1 : 0;
        if(take){ dsc[2] += val - dsc[3+g]; dsc[3+g]=val; sel_s[node]=1; }
        ctl[2]=take;
      }
      __syncthreads();
      if(ctl[2]){
        dummy_s[base+tid]=sbuf[tid];
        if(isnb) rej_s[base+tid]=1;
      }
      __syncthreads();
    }
  }

  for(int t=tid;t<NN;t+=256){
    float sv = sel_s[t]?1.0f:0.0f;
    selw[t]=sv; out_sel[t]=sv;
  }
}

// ---------------- outputs ----------------
__global__ void k_xpool(const float* __restrict__ x, const float* __restrict__ selw, float* __restrict__ out){
  int t = blockIdx.x*256+threadIdx.x;
  if(t >= NN*(DD/4)) return;
  int i = t >> 7;
  float s = selw[i];
  float4 v = ((const float4*)x)[t];
  v.x*=s; v.y*=s; v.z*=s; v.w*=s;
  ((float4*)out)[t] = v;
}

__global__ void k_adj(const u32* __restrict__ bm, const u32* __restrict__ bm2,
                      const float* __restrict__ selw, float* __restrict__ outadj){
  int r = blockIdx.x;
  int c = blockIdx.y*256 + threadIdx.x;
  float val = 0.0f;
  if ((r>>8)==(c>>8) && r!=c && selw[r]!=0.0f && selw[c]!=0.0f){
    int lc = c & 255;
    u32 any = (bm2[r*NWORDS + (lc>>5)] >> (lc&31)) & 1u; // A2>0
    if(!any){
      #pragma unroll
      for(int w=0;w<NWORDS;++w) any |= (bm2[r*NWORDS+w] & bm[c*NWORDS+w]); // A3>0
    }
    val = any ? 1.0f : 0.0f;
  }
  outadj[(size_t)r*2048 + c] = val;
}

extern "C" void kernel_launch(void* const* d_in, const int* in_sizes, int n_in,
                              void* d_out, int out_size, void* d_ws, size_t ws_size,
                              hipStream_t stream){
  const float* x  = (const float*)d_in[0];
  const int* ei   = (const int*)d_in[1];
  const float* w11=(const float*)d_in[3];  const float* b11=(const float*)d_in[4];
  const float* w12=(const float*)d_in[5];  const float* b12=(const float*)d_in[6];
  const float* w13=(const float*)d_in[7];  const float* b13=(const float*)d_in[8];
  const float* w21=(const float*)d_in[9];  const float* b21=(const float*)d_in[10];
  const float* w22=(const float*)d_in[11]; const float* b22=(const float*)d_in[12];
  const float* w23=(const float*)d_in[13]; const float* b23=(const float*)d_in[14];
  const float* w31=(const float*)d_in[15]; const float* b31=(const float*)d_in[16];
  const float* w32=(const float*)d_in[17]; const float* b32=(const float*)d_in[18];
  const float* w33=(const float*)d_in[19]; const float* b33=(const float*)d_in[20];

  char* ws = (char*)d_ws;
  u32* bm    = (u32*)(ws + 0);
  u32* bm2   = (u32*)(ws + 65536);
  int* deg   = (int*)(ws + 131072);
  float* Vn  = (float*)(ws + 139264);
  float* ent = (float*)(ws + 147456);
  float* uarr= (float*)(ws + 155648);
  float* prob= (float*)(ws + 163840);
  int* order = (int*)(ws + 172032);
  float* selw= (float*)(ws + 180224);
  float* buf0= (float*)(ws + (1<<20));
  float* buf1= (float*)(ws + (1<<20) + (size_t)NN*DD*4);

  float* out = (float*)d_out;
  float* out_xp   = out;
  float* out_adj  = out + 1048576;
  float* out_sel  = out + 1048576 + 4194304;
  float* out_loss = out + 1048576 + 4194304 + 2048;

  hipFuncSetAttribute((const void*)k_scan, hipFuncAttributeMaxDynamicSharedMemorySize, 98304);

  k_zero_bm<<<64,256,0,stream>>>(bm);
  k_scatter<<<128,256,0,stream>>>(ei, bm);
  k_bm2_deg<<<8,256,0,stream>>>(bm, bm2, deg);
  k_vn<<<512,256,0,stream>>>(x, bm, deg, Vn);
  k_softent<<<8,256,0,stream>>>(Vn, ent);
  k_u<<<8,256,0,stream>>>(bm, ent, uarr);
  k_h1<<<4096,256,0,stream>>>(uarr, w11, b11, buf0);
  dim3 gg(32,8);
  k_gemm<0><<<gg,256,0,stream>>>(buf0, w12, b12, buf1);
  k_gemm<1><<<gg,256,0,stream>>>(buf1, w13, b13, buf0);
  k_spmm_add<<<512,256,0,stream>>>(buf0, bm, buf1);
  k_gemm<0><<<gg,256,0,stream>>>(buf1, w21, b21, buf0);
  k_gemm<0><<<gg,256,0,stream>>>(buf0, w22, b22, buf1);
  k_gemm<1><<<gg,256,0,stream>>>(buf1, w23, b23, buf0);
  k_spmm_add<<<512,256,0,stream>>>(buf0, bm, buf1);
  k_gemm<0><<<gg,256,0,stream>>>(buf1, w31, b31, buf0);
  k_gemm<0><<<gg,256,0,stream>>>(buf0, w32, b32, buf1);
  k_gemv_prob<<<512,256,0,stream>>>(buf1, w33, b33, prob);
  k_sort<<<1,1024,0,stream>>>(prob, order);
  k_scan<<<1,256,95376,stream>>>(bm, deg, ent, prob, order, selw, out_sel, out_loss);
  k_xpool<<<1024,256,0,stream>>>(x, selw, out_xp);
  dim3 ga(2048,8);
  k_adj<<<ga,256,0,stream>>>(bm, bm2, selw, out_adj);
}